// Round 4
// baseline (215.205 us; speedup 1.0000x reference)
//
#include <hip/hip_runtime.h>

// ---------------------------------------------------------------------------
// MultiHeadedAttention: B=2, S=2048, Dm=1024, H=16, hd=64
// R4: pipeline restructure.
//  - gemm_qkv: BK=64, swizzled LDS, XCD-swizzled grid. Q/K col-tiles -> qkv2
//    [4096][2048]; V col-tiles computed TRANSPOSED (swap MFMA operands) and
//    written directly to vT[b][h][d][s]  (transpose_v kernel eliminated).
//  - attn: 64-row Q tiles, 4-wave blocks, grid 1024 -> 4 blocks/CU.
//  - gemm_out: 128x64 tiles, grid 512 -> 2 blocks/CU.
// ---------------------------------------------------------------------------

typedef __bf16 bf16x8 __attribute__((ext_vector_type(8)));
typedef float f32x4 __attribute__((ext_vector_type(4)));
typedef int i32x4 __attribute__((ext_vector_type(4)));

#define B_   2
#define S_   2048
#define DM   1024
#define NH   16
#define HD   64
#define N3   3072
#define M_   4096   // B_*S_

// 0.125 (1/sqrt(64)) * log2(e)
#define SCALE_LOG2E 0.180336884f

__device__ __forceinline__ unsigned short f2bf(float f) {
  unsigned int u = __float_as_uint(f);
  u += 0x7fffu + ((u >> 16) & 1u);   // round-to-nearest-even
  return (unsigned short)(u >> 16);
}

__device__ __forceinline__ void gload_lds16(void* lds, const void* g) {
  __builtin_amdgcn_global_load_lds(
      (__attribute__((address_space(1))) void*)g,
      (__attribute__((address_space(3))) void*)lds, 16, 0, 0);
}

// ---------------- fp32 -> bf16 elementwise (query) -------------------------
__global__ __launch_bounds__(256) void f32_to_bf16_vec(
    const float4* __restrict__ in, unsigned short* __restrict__ out, int n4) {
  int i = blockIdx.x * 256 + threadIdx.x;
  if (i < n4) {
    float4 v = in[i];
    ushort4 o;
    o.x = f2bf(v.x); o.y = f2bf(v.y); o.z = f2bf(v.z); o.w = f2bf(v.w);
    *(ushort4*)(&out[(size_t)i * 4]) = o;
  }
}

// ---------------- fp32 [R][C] -> bf16 [C][R] transpose (weights) -----------
__global__ __launch_bounds__(256) void transpose_f32_bf16(
    const float* __restrict__ in, unsigned short* __restrict__ out, int R, int C) {
  __shared__ float tile[32][33];
  const int tx = threadIdx.x, ty = threadIdx.y;
  const int x = blockIdx.x * 32 + tx;
  const int y0 = blockIdx.y * 32;
#pragma unroll
  for (int j = 0; j < 32; j += 8)
    tile[ty + j][tx] = in[(size_t)(y0 + ty + j) * C + x];
  __syncthreads();
  const int ox = y0 + tx;
  const int oy0 = blockIdx.x * 32;
#pragma unroll
  for (int j = 0; j < 32; j += 8)
    out[(size_t)(oy0 + ty + j) * R + ox] = f2bf(tile[tx][ty + j]);
}

// ---------------- gemm_qkv: qkv = qbf @ w_in_t^T, BK=64 --------------------
// grid 768 (1-D, XCD-swizzled: xcd owns 3 col-tiles). col-tile < 16 -> Q/K
// rows into qkv2[4096][2048]; col-tile >= 16 -> V computed transposed via
// swapped MFMA operands, written to vT[b][h][d][s].
__global__ __launch_bounds__(256) void gemm_qkv(
    const unsigned short* __restrict__ A,   // qbf [4096][1024]
    const unsigned short* __restrict__ Bt,  // w_in_t [3072][1024]
    unsigned short* __restrict__ qkv2,      // [4096][2048]
    unsigned short* __restrict__ vT) {      // [2][16][64][2048]
  __shared__ __align__(16) unsigned short a_sm[128 * 64];
  __shared__ __align__(16) unsigned short b_sm[128 * 64];
  const int id = blockIdx.x;
  const int xcd = id & 7, j8 = id >> 3;           // j8: 0..95
  const int ct = xcd * 3 + (j8 % 3);              // 0..23
  const int rt = j8 / 3;                          // 0..31
  const bool isv = ct >= 16;
  const int row0 = rt * 128, col0 = ct * 128;

  const int tid = threadIdx.x;
  const int lane = tid & 63, wave = tid >> 6;
  const int quad = lane >> 4, l15 = lane & 15;
  const int sw = l15 & 7;
  const int wm = (wave >> 1) * 64, wn = (wave & 1) * 64;

  f32x4 acc[4][4];
#pragma unroll
  for (int i = 0; i < 4; i++)
#pragma unroll
    for (int j = 0; j < 4; j++) acc[i][j] = (f32x4){0.f, 0.f, 0.f, 0.f};

  // staging: phys chunk tid&7 of row (tid>>3)+rnd*32 holds logical chunk
  // (tid&7)^((tid>>3)&7)  (XOR swizzle; key = row&7, invariant across rnd)
  const int c_src = ((tid & 7) ^ ((tid >> 3) & 7)) * 8;
  const int r_st = tid >> 3;
  const unsigned short* Ab = A + (size_t)(row0 + r_st) * DM + c_src;
  const unsigned short* Bb = Bt + (size_t)(col0 + r_st) * DM + c_src;

  for (int k0 = 0; k0 < DM; k0 += 64) {
    __syncthreads();
#pragma unroll
    for (int rnd = 0; rnd < 4; rnd++) {
      gload_lds16(&a_sm[tid * 8 + rnd * 2048], Ab + k0 + (size_t)rnd * 32 * DM);
      gload_lds16(&b_sm[tid * 8 + rnd * 2048], Bb + k0 + (size_t)rnd * 32 * DM);
    }
    __syncthreads();

    bf16x8 af[4][2], bfr[4][2];
#pragma unroll
    for (int i = 0; i < 4; i++)
#pragma unroll
      for (int h = 0; h < 2; h++) {
        const int ch = ((h * 4 + quad) ^ sw) << 3;
        af[i][h]  = *(const bf16x8*)&a_sm[(wm + i * 16 + l15) * 64 + ch];
        bfr[i][h] = *(const bf16x8*)&b_sm[(wn + i * 16 + l15) * 64 + ch];
      }
    if (!isv) {
#pragma unroll
      for (int i = 0; i < 4; i++)
#pragma unroll
        for (int j = 0; j < 4; j++)
#pragma unroll
          for (int h = 0; h < 2; h++)
            acc[i][j] = __builtin_amdgcn_mfma_f32_16x16x32_bf16(af[i][h], bfr[j][h], acc[i][j], 0, 0, 0);
    } else {
#pragma unroll
      for (int i = 0; i < 4; i++)
#pragma unroll
        for (int j = 0; j < 4; j++)
#pragma unroll
          for (int h = 0; h < 2; h++)
            acc[i][j] = __builtin_amdgcn_mfma_f32_16x16x32_bf16(bfr[i][h], af[j][h], acc[i][j], 0, 0, 0);
    }
  }

  if (!isv) {
    // D[m=token][n=qk-col]: direct rows into qkv2
#pragma unroll
    for (int i = 0; i < 4; i++)
#pragma unroll
      for (int j = 0; j < 4; j++)
#pragma unroll
        for (int r = 0; r < 4; r++) {
          const int row = row0 + wm + i * 16 + quad * 4 + r;
          const int col = col0 + wn + j * 16 + l15;
          qkv2[(size_t)row * 2048 + col] = f2bf(acc[i][j][r]);
        }
  } else {
    // D[m=vdim][n=token]: transposed write to vT[b][h][d][s]
    const int head = ((col0 - 2048) >> 6) + (wn >> 6);
    const int bidx = row0 >> 11;
    const int s_base = (row0 & 2047) + wm;
#pragma unroll
    for (int i = 0; i < 4; i++)
#pragma unroll
      for (int j = 0; j < 4; j++)
#pragma unroll
        for (int r = 0; r < 4; r++) {
          const int d = i * 16 + quad * 4 + r;
          const int s = s_base + j * 16 + l15;
          vT[((size_t)((bidx * NH + head) * HD + d)) * S_ + s] = f2bf(acc[i][j][r]);
        }
  }
}

// ---------------- fused causal attention v4 --------------------------------
// grid (32, NH, B), 256 threads (4 waves), wave owns 16 q rows (64-row tile).
// Double-buffered K/V (XOR swizzle), one barrier per key tile.
// S^T = mfma(K,Q); P^T built in-register via ds_bpermute; O^T = mfma(V^T,P^T).
__global__ __launch_bounds__(256) void attn_fused4(
    const unsigned short* __restrict__ qkv2,   // [4096][2048] Q||K
    const unsigned short* __restrict__ vT,     // [2][16][64][2048]
    unsigned short* __restrict__ attnout) {    // [4096][1024]
  const int h = blockIdx.y, b = blockIdx.z;
  const int qt = (b == 0) ? blockIdx.x : (31 - blockIdx.x);
  const int tid = threadIdx.x;
  const int lane = tid & 63, wave = tid >> 6;   // wave 0..3
  const int quad = lane >> 4, l15 = lane & 15;
  const int sw = l15 & 7;

  __shared__ __align__(16) unsigned short k_sm[2 * 4096];   // [buf][64 keys][64 d]
  __shared__ __align__(16) unsigned short vt_sm[2 * 4096];  // [buf][64 d][64 keys]

  const int Q0 = qt * 64;
  const int qrow = Q0 + wave * 16 + l15;
  const int wrow0 = Q0 + wave * 16;

  bf16x8 qf[2];
  {
    const unsigned short* qp = qkv2 + (size_t)(b * S_ + qrow) * 2048 + h * HD + quad * 8;
    qf[0] = *(const bf16x8*)qp;
    qf[1] = *(const bf16x8*)(qp + 32);
  }

  f32x4 o[4];
#pragma unroll
  for (int n = 0; n < 4; n++) o[n] = (f32x4){0.f, 0.f, 0.f, 0.f};
  float lsum = 0.f;

  // staging: rows r0s, r0s+32; phys chunk tid&7 holds logical (tid&7)^(r&7)
  const int r0s = tid >> 3;                       // 0..31
  const int gch = ((tid & 7) ^ (r0s & 7)) * 8;
  const unsigned short* kgb = qkv2 + (size_t)(b * S_ + r0s) * 2048 + DM + h * HD + gch;
  const unsigned short* vgb = vT + (size_t)((b * NH + h) * HD + r0s) * S_ + gch;

  const int addrA = (((quad * 2) & 3) * 16 + l15) * 4;
  const int addrB = (((quad * 2 + 1) & 3) * 16 + l15) * 4;

  const int nt = qt + 1;
  // prefetch tile 0
  gload_lds16(&k_sm[tid * 8], kgb);
  gload_lds16(&k_sm[2048 + tid * 8], kgb + (size_t)32 * 2048);
  gload_lds16(&vt_sm[tid * 8], vgb);
  gload_lds16(&vt_sm[2048 + tid * 8], vgb + (size_t)32 * S_);

  for (int t = 0; t < nt; t++) {
    __syncthreads();   // buf[t&1] staged; buf[(t+1)&1] readers done
    if (t + 1 < nt) {
      const int nb = ((t + 1) & 1) * 4096;
      const unsigned short* kg = kgb + (size_t)(t + 1) * 64 * 2048;
      const unsigned short* vg = vgb + (t + 1) * 64;
      gload_lds16(&k_sm[nb + tid * 8], kg);
      gload_lds16(&k_sm[nb + 2048 + tid * 8], kg + (size_t)32 * 2048);
      gload_lds16(&vt_sm[nb + tid * 8], vg);
      gload_lds16(&vt_sm[nb + 2048 + tid * 8], vg + (size_t)32 * S_);
    }

    const unsigned short* kb = &k_sm[(t & 1) * 4096];
    const unsigned short* vb = &vt_sm[(t & 1) * 4096];

    // S^T = K Q^T : lane holds keys mb*16+quad*4+r, qrow = l15
    f32x4 s[4];
#pragma unroll
    for (int mb = 0; mb < 4; mb++) s[mb] = (f32x4){0.f, 0.f, 0.f, 0.f};
#pragma unroll
    for (int mb = 0; mb < 4; mb++) {
      const int ro = (mb * 16 + l15) * 64;
      bf16x8 kf0 = *(const bf16x8*)&kb[ro + ((quad ^ sw) << 3)];
      bf16x8 kf1 = *(const bf16x8*)&kb[ro + (((4 + quad) ^ sw) << 3)];
      s[mb] = __builtin_amdgcn_mfma_f32_16x16x32_bf16(kf0, qf[0], s[mb], 0, 0, 0);
      s[mb] = __builtin_amdgcn_mfma_f32_16x16x32_bf16(kf1, qf[1], s[mb], 0, 0, 0);
    }

    // P = exp(S/8); mask only the diagonal tile (t == qt)
    if (t < qt) {
#pragma unroll
      for (int mb = 0; mb < 4; mb++)
#pragma unroll
        for (int r = 0; r < 4; r++)
          s[mb][r] = exp2f(s[mb][r] * SCALE_LOG2E);
    } else {
      const int kb0 = t * 64 + quad * 4;
#pragma unroll
      for (int mb = 0; mb < 4; mb++)
#pragma unroll
        for (int r = 0; r < 4; r++) {
          const float e = exp2f(s[mb][r] * SCALE_LOG2E);
          s[mb][r] = (kb0 + mb * 16 + r <= qrow) ? e : 0.f;
        }
    }
#pragma unroll
    for (int mb = 0; mb < 4; mb++)
      lsum += (s[mb][0] + s[mb][1]) + (s[mb][2] + s[mb][3]);

    // pack to bf16 pairs
    int pk[4][2];
#pragma unroll
    for (int mb = 0; mb < 4; mb++) {
      const unsigned u0 = __float_as_uint(s[mb][0]) + 0x8000u;
      const unsigned u1 = __float_as_uint(s[mb][1]) + 0x8000u;
      const unsigned u2 = __float_as_uint(s[mb][2]) + 0x8000u;
      const unsigned u3 = __float_as_uint(s[mb][3]) + 0x8000u;
      pk[mb][0] = (int)__builtin_amdgcn_perm(u1, u0, 0x07060302u);
      pk[mb][1] = (int)__builtin_amdgcn_perm(u3, u2, 0x07060302u);
    }

    // O^T += V^T P^T
    const bool hi = quad >= 2;
#pragma unroll
    for (int ks = 0; ks < 2; ks++) {
      const int m0 = 2 * ks, m1 = m0 + 1;
      const int f0a = __builtin_amdgcn_ds_bpermute(addrA, pk[m0][0]);
      const int f0b = __builtin_amdgcn_ds_bpermute(addrA, pk[m1][0]);
      const int f1a = __builtin_amdgcn_ds_bpermute(addrA, pk[m0][1]);
      const int f1b = __builtin_amdgcn_ds_bpermute(addrA, pk[m1][1]);
      const int f2a = __builtin_amdgcn_ds_bpermute(addrB, pk[m0][0]);
      const int f2b = __builtin_amdgcn_ds_bpermute(addrB, pk[m1][0]);
      const int f3a = __builtin_amdgcn_ds_bpermute(addrB, pk[m0][1]);
      const int f3b = __builtin_amdgcn_ds_bpermute(addrB, pk[m1][1]);
      i32x4 fr;
      fr.x = hi ? f0b : f0a;
      fr.y = hi ? f1b : f1a;
      fr.z = hi ? f2b : f2a;
      fr.w = hi ? f3b : f3a;
      const bf16x8 pfrag = __builtin_bit_cast(bf16x8, fr);
#pragma unroll
      for (int mb = 0; mb < 4; mb++) {
        const int ro = (mb * 16 + l15) * 64;
        bf16x8 vf = *(const bf16x8*)&vb[ro + (((ks * 4 + quad) ^ sw) << 3)];
        o[mb] = __builtin_amdgcn_mfma_f32_16x16x32_bf16(vf, pfrag, o[mb], 0, 0, 0);
      }
    }
  }

  // normalize + write
  float l = lsum;
  l += __shfl_xor(l, 16);
  l += __shfl_xor(l, 32);
  const float inv = 1.0f / l;
  const size_t grow = (size_t)(b * S_ + qrow);
#pragma unroll
  for (int mb = 0; mb < 4; mb++) {
    ushort4 w;
    w.x = f2bf(o[mb][0] * inv);
    w.y = f2bf(o[mb][1] * inv);
    w.z = f2bf(o[mb][2] * inv);
    w.w = f2bf(o[mb][3] * inv);
    *(ushort4*)&attnout[grow * DM + h * HD + mb * 16 + quad * 4] = w;
  }
}

// ---------------- gemm_out: out[4096][1024] = attn @ w_out_t^T (fp32) ------
// tile 128(M) x 64(N), BK=32, grid 512 (2 blocks/CU), 4 waves each 32x64.
__global__ __launch_bounds__(256) void gemm_out(
    const unsigned short* __restrict__ A,   // attn [4096][1024]
    const unsigned short* __restrict__ Bt,  // w_out_t [1024][1024]
    float* __restrict__ C) {                // [4096][1024]
  __shared__ __align__(16) unsigned short a_sm[128 * 32];
  __shared__ __align__(16) unsigned short b_sm[64 * 32];
  const int id = blockIdx.x;
  const int ctile = id & 15, rtile = id >> 4;
  const int row0 = rtile * 128, col0 = ctile * 64;

  const int tid = threadIdx.x;
  const int lane = tid & 63, wave = tid >> 6;
  const int quad = lane >> 4, l15 = lane & 15;
  const int wm = wave * 32;

  f32x4 acc[2][4];
#pragma unroll
  for (int i = 0; i < 2; i++)
#pragma unroll
    for (int j = 0; j < 4; j++) acc[i][j] = (f32x4){0.f, 0.f, 0.f, 0.f};

  const int rA = tid >> 2, cA = (tid & 3) * 8;

  for (int k0 = 0; k0 < DM; k0 += 32) {
    __syncthreads();
    gload_lds16(&a_sm[tid * 8],        &A[(size_t)(row0 + rA) * DM + k0 + cA]);
    gload_lds16(&a_sm[tid * 8 + 2048], &A[(size_t)(row0 + rA + 64) * DM + k0 + cA]);
    gload_lds16(&b_sm[tid * 8],        &Bt[(size_t)(col0 + rA) * DM + k0 + cA]);
    __syncthreads();

    bf16x8 af[2], bf[4];
#pragma unroll
    for (int i = 0; i < 2; i++)
      af[i] = *(const bf16x8*)&a_sm[(wm + i * 16 + l15) * 32 + quad * 8];
#pragma unroll
    for (int j = 0; j < 4; j++)
      bf[j] = *(const bf16x8*)&b_sm[(j * 16 + l15) * 32 + quad * 8];
#pragma unroll
    for (int i = 0; i < 2; i++)
#pragma unroll
      for (int j = 0; j < 4; j++)
        acc[i][j] = __builtin_amdgcn_mfma_f32_16x16x32_bf16(af[i], bf[j], acc[i][j], 0, 0, 0);
  }

#pragma unroll
  for (int i = 0; i < 2; i++)
#pragma unroll
    for (int j = 0; j < 4; j++)
#pragma unroll
      for (int r = 0; r < 4; r++) {
        const int row = row0 + wm + i * 16 + quad * 4 + r;
        const int col = col0 + j * 16 + l15;
        C[(size_t)row * DM + col] = acc[i][j][r];
      }
}

// ---------------------------------------------------------------------------
extern "C" void kernel_launch(void* const* d_in, const int* in_sizes, int n_in,
                              void* d_out, int out_size, void* d_ws, size_t ws_size,
                              hipStream_t stream) {
  const float* query = (const float*)d_in[0];   // [4096][1024]
  const float* w_in  = (const float*)d_in[1];   // [1024][3072]
  const float* w_out = (const float*)d_in[2];   // [1024][1024]
  float* out = (float*)d_out;                   // [4096][1024] fp32

  char* ws = (char*)d_ws;
  unsigned short* qbf     = (unsigned short*)(ws);                 //  8 MB
  unsigned short* w_in_t  = (unsigned short*)(ws + 8388608);       //  6 MB [3072][1024]
  unsigned short* w_out_t = (unsigned short*)(ws + 14680064);      //  2 MB [1024][1024]
  unsigned short* qkv2    = (unsigned short*)(ws + 16777216);      // 16 MB [4096][2048]
  unsigned short* vT      = (unsigned short*)(ws + 33554432);      //  8 MB [2][16][64][2048]
  unsigned short* attn    = (unsigned short*)(ws + 41943040);      //  8 MB [4096][1024]

  // 1. convert query fp32 -> bf16
  f32_to_bf16_vec<<<dim3(M_ * DM / 1024), dim3(256), 0, stream>>>(
      (const float4*)query, qbf, M_ * DM / 4);
  // 2. transpose+convert weights
  transpose_f32_bf16<<<dim3(N3 / 32, DM / 32), dim3(32, 8), 0, stream>>>(w_in, w_in_t, DM, N3);
  transpose_f32_bf16<<<dim3(DM / 32, DM / 32), dim3(32, 8), 0, stream>>>(w_out, w_out_t, DM, DM);
  // 3. qkv2 (Q||K rows) + vT (transposed V) in one GEMM
  gemm_qkv<<<dim3(768), dim3(256), 0, stream>>>(qbf, w_in_t, qkv2, vT);
  // 4. fused causal attention -> attn [4096][1024] bf16
  attn_fused4<<<dim3(32, NH, B_), dim3(256), 0, stream>>>(qkv2, vT, attn);
  // 5. out = attn @ W_out   [4096][1024] fp32
  gemm_out<<<dim3(512), dim3(256), 0, stream>>>(attn, w_out_t, out);
}